// Round 9
// baseline (197.062 us; speedup 1.0000x reference)
//
#include <hip/hip_runtime.h>
#include <hip/hip_bf16.h>

typedef unsigned short u16;
typedef unsigned int u32;
typedef __bf16 bf16x8 __attribute__((ext_vector_type(8)));
typedef float f32x4 __attribute__((ext_vector_type(4)));
typedef float f32x16 __attribute__((ext_vector_type(16)));

#define DMODEL 1024
#define NH 16
#define DH 64
#define BB 2
#define TT 2048
#define MM 4096   // BB*TT
#define NQKV 3072
#define KVB 64    // attention key-tile

// Q pre-scale: Dh^-0.5 * log2(e) -> scores land in log2 domain (P = v_exp_f32 direct)
#define QSCALE 0.18033688011112042f

static __device__ __forceinline__ u16 f2bf(float f) {
  u32 u = __float_as_uint(f);
  u = (u + 0x7FFFu + ((u >> 16) & 1u)) >> 16;  // RNE
  return (u16)u;
}

static __device__ __forceinline__ u32 pk2bf(float a, float b) {
  u16 ua = __builtin_bit_cast(u16, (__bf16)a);
  u16 ub = __builtin_bit_cast(u16, (__bf16)b);
  return (u32)ua | ((u32)ub << 16);
}

static __device__ __forceinline__ float fexp2(float x) {
#if __has_builtin(__builtin_amdgcn_exp2f)
  return __builtin_amdgcn_exp2f(x);
#else
  float r; asm("v_exp_f32 %0, %1" : "=v"(r) : "v"(x)); return r;
#endif
}

static __device__ __forceinline__ float max3f(float a, float b, float c) {
  return fmaxf(fmaxf(a, b), c);  // fuses to v_max3_f32
}

static __device__ __forceinline__ void gload16(const u16* g, u16* l) {
  __builtin_amdgcn_global_load_lds(
      (const __attribute__((address_space(1))) void*)g,
      (__attribute__((address_space(3))) void*)l, 16, 0, 0);
}

// Fused f32->bf16 convert: x | wqkv | wproj (dst regions contiguous in ws).
#define N4X  (MM * DMODEL / 4)
#define N4W  (NQKV * DMODEL / 4)
#define N4P  (DMODEL * DMODEL / 4)
__global__ __launch_bounds__(256) void cvt_all(const float* __restrict__ x,
                                               const float* __restrict__ wqkv,
                                               const float* __restrict__ wproj,
                                               u16* __restrict__ dst) {
  int i = blockIdx.x * 256 + threadIdx.x;
  const float* src;
  int j = i;
  if (i < N4X) {
    src = x;
  } else if (i < N4X + N4W) {
    src = wqkv; j = i - N4X;
  } else {
    src = wproj; j = i - (N4X + N4W);
  }
  float4 v = reinterpret_cast<const float4*>(src)[j];
  ushort4 o;
  o.x = f2bf(v.x); o.y = f2bf(v.y); o.z = f2bf(v.z); o.w = f2bf(v.w);
  reinterpret_cast<ushort4*>(dst)[i] = o;
}

// ---------- GEMM: 128x128 tile, K=1024, 2-phase pipelined ----------
static __device__ __forceinline__ void gemm_stage(
    const u16* __restrict__ A, const u16* __restrict__ B, u16* As, u16* Bs,
    int r0, int o0, int r1, int o1, int c0, int c1, int kcol) {
  gload16(A + (size_t)r0 * DMODEL + kcol + o0, As + c0 * 8);
  gload16(A + (size_t)r1 * DMODEL + kcol + o1, As + c1 * 8);
  gload16(B + (size_t)r0 * DMODEL + kcol + o0, Bs + c0 * 8);
  gload16(B + (size_t)r1 * DMODEL + kcol + o1, Bs + c1 * 8);
}

static __device__ __forceinline__ void gemm128_mainloop(
    const u16* __restrict__ Abase, const u16* __restrict__ Bbase,
    u16* As, u16* Bs, f32x4 (&acc)[4][4]) {
  const int tid = threadIdx.x;
  const int lane = tid & 63;
  const int w = tid >> 6;
  const int rowg = lane >> 4, col = lane & 15;
  const int wm = w >> 1, wn = w & 1;
  const int c0 = tid, c1 = tid + 256;
  const int r0 = c0 >> 2, o0 = (c0 & 3) * 8;
  const int r1 = c1 >> 2, o1 = (c1 & 3) * 8;

  gemm_stage(Abase, Bbase, As, Bs, r0, o0, r1, o1, c0, c1, 0);
  asm volatile("s_waitcnt vmcnt(0)" ::: "memory");
  __builtin_amdgcn_s_barrier();

  int sel = 0;
  for (int kt = 0; kt < DMODEL / 32; ++kt) {
    const int kn = ((kt + 1) & (DMODEL / 32 - 1)) * 32;
    const int ns = sel ^ 1;
    gemm_stage(Abase, Bbase, As + ns * 4096, Bs + ns * 4096, r0, o0, r1, o1, c0, c1, kn);
    const u16* as = As + sel * 4096;
    const u16* bs = Bs + sel * 4096;
    bf16x8 af[4], bfr[4];
#pragma unroll
    for (int i = 0; i < 4; ++i)
      af[i] = *reinterpret_cast<const bf16x8*>(as + (wm * 64 + i * 16 + col) * 32 + rowg * 8);
#pragma unroll
    for (int j = 0; j < 4; ++j)
      bfr[j] = *reinterpret_cast<const bf16x8*>(bs + (wn * 64 + j * 16 + col) * 32 + rowg * 8);
#pragma unroll
    for (int i = 0; i < 4; ++i)
#pragma unroll
      for (int j = 0; j < 4; ++j)
        acc[i][j] = __builtin_amdgcn_mfma_f32_16x16x32_bf16(af[i], bfr[j], acc[i][j], 0, 0, 0);
    asm volatile("s_waitcnt vmcnt(0)" ::: "memory");
    __builtin_amdgcn_s_barrier();
    sel = ns;
  }
}

// QKV projection: C[m,n] = x[m,:] . Wqkv[n,:]; scatter to q/k/vt, q pre-scaled.
__global__ __launch_bounds__(256, 3) void qkv_gemm(
    const u16* __restrict__ xb, const u16* __restrict__ wb,
    u16* __restrict__ qb, u16* __restrict__ kb, u16* __restrict__ vtb) {
  __shared__ u16 As[2 * 128 * 32];
  __shared__ u16 Bs[2 * 128 * 32];
  f32x4 acc[4][4];
#pragma unroll
  for (int i = 0; i < 4; ++i)
#pragma unroll
    for (int j = 0; j < 4; ++j) acc[i][j] = (f32x4){0.f, 0.f, 0.f, 0.f};
  gemm128_mainloop(xb + (size_t)blockIdx.y * 128 * DMODEL,
                   wb + (size_t)blockIdx.x * 128 * DMODEL, As, Bs, acc);
  const int lane = threadIdx.x & 63, w = threadIdx.x >> 6;
  const int rowg = lane >> 4, col = lane & 15, wm = w >> 1, wn = w & 1;
#pragma unroll
  for (int i = 0; i < 4; ++i) {
#pragma unroll
    for (int j = 0; j < 4; ++j) {
#pragma unroll
      for (int r = 0; r < 4; ++r) {
        int m = blockIdx.y * 128 + wm * 64 + i * 16 + rowg * 4 + r;
        int n = blockIdx.x * 128 + wn * 64 + j * 16 + col;
        int b = m >> 11, t = m & (TT - 1);
        int s = n >> 10, h = (n >> 6) & 15, d = n & 63;
        int bh = b * NH + h;
        float v = acc[i][j][r];
        if (s == 0)      qb[((size_t)bh * TT + t) * DH + d] = f2bf(v * QSCALE);
        else if (s == 1) kb[((size_t)bh * TT + t) * DH + d] = f2bf(v);
        else             vtb[((size_t)bh * DH + d) * TT + t] = f2bf(v);
      }
    }
  }
}

// Output projection: out[m,n] = ob[m,:] . Wproj[n,:], f32 out.
__global__ __launch_bounds__(256, 3) void proj_gemm(
    const u16* __restrict__ ab, const u16* __restrict__ wb, float* __restrict__ out) {
  __shared__ u16 As[2 * 128 * 32];
  __shared__ u16 Bs[2 * 128 * 32];
  f32x4 acc[4][4];
#pragma unroll
  for (int i = 0; i < 4; ++i)
#pragma unroll
    for (int j = 0; j < 4; ++j) acc[i][j] = (f32x4){0.f, 0.f, 0.f, 0.f};
  gemm128_mainloop(ab + (size_t)blockIdx.y * 128 * DMODEL,
                   wb + (size_t)blockIdx.x * 128 * DMODEL, As, Bs, acc);
  const int lane = threadIdx.x & 63, w = threadIdx.x >> 6;
  const int rowg = lane >> 4, col = lane & 15, wm = w >> 1, wn = w & 1;
#pragma unroll
  for (int i = 0; i < 4; ++i) {
#pragma unroll
    for (int j = 0; j < 4; ++j) {
#pragma unroll
      for (int r = 0; r < 4; ++r) {
        int m = blockIdx.y * 128 + wm * 64 + i * 16 + rowg * 4 + r;
        int n = blockIdx.x * 128 + wn * 64 + j * 16 + col;
        out[(size_t)m * DMODEL + n] = acc[i][j][r];
      }
    }
  }
}

// ---------- Flash attention: BARRIER-FREE dataflow. 4 waves x 32 q, 32x32x16 MFMA, ----------
// K/V frags global->reg (L1/L2 cached, 16B/lane contiguous), in-register P via
// cvt_pk + permlane32_swap. No LDS staging, no in-loop barriers — waves drift freely.
// Grid: blockIdx.x = bh so all q-tiles of a head share an XCD (K/V L2-local).
#define LOADK_SET(T, KA)                                                              \
  do {                                                                                \
    const u16* kt_ = kbase + (size_t)(T) * (KVB * DH);                                \
    _Pragma("unroll") for (int kf_ = 0; kf_ < 2; ++kf_)                               \
      _Pragma("unroll") for (int ds_ = 0; ds_ < 4; ++ds_)                             \
        KA[kf_ * 4 + ds_] = *reinterpret_cast<const bf16x8*>(                         \
            kt_ + (kf_ * 32 + col) * DH + ds_ * 16 + h * 8);                          \
  } while (0)

#define LOADV_SET(T, VA)                                                              \
  do {                                                                                \
    const u16* vt_ = vbase + (T) * KVB;                                               \
    _Pragma("unroll") for (int df_ = 0; df_ < 2; ++df_)                               \
      _Pragma("unroll") for (int ks_ = 0; ks_ < 4; ++ks_)                             \
        VA[df_ * 4 + ks_] = *reinterpret_cast<const bf16x8*>(                         \
            vt_ + (size_t)(df_ * 32 + col) * TT + ks_ * 16 + h * 8);                  \
  } while (0)

__global__ __launch_bounds__(256, 2) void attn_kernel(
    const u16* __restrict__ qb, const u16* __restrict__ kb,
    const u16* __restrict__ vtb, const unsigned char* __restrict__ mask,
    u16* __restrict__ ob) {
  __shared__ u16 Ol[128 * 64];         // 16KB epilogue transpose buffer
  __shared__ unsigned char maskb[TT];
  __shared__ u32 mflag;

  const int tid = threadIdx.x;
  const int lane = tid & 63, w = tid >> 6;
  const int col = lane & 31, h = lane >> 5;
  const int bh = blockIdx.x, qt = blockIdx.y;   // bh-major: XCD = bh % 8
  const int b = bh >> 4;

  if (tid == 0) mflag = 0;
  __syncthreads();

  {  // preload mask bytes; per-tile flag bits (8B/thread, 64B per tile)
    const u32* mg = reinterpret_cast<const u32*>(mask + (size_t)b * TT);
    u32 m0 = mg[tid * 2], m1 = mg[tid * 2 + 1];
    *reinterpret_cast<u32*>(maskb + tid * 8) = m0;
    *reinterpret_cast<u32*>(maskb + tid * 8 + 4) = m1;
    if (m0 | m1) atomicOr(&mflag, 1u << (tid >> 3));
  }

  const int qrow0 = qt * 128 + w * 32;
  const u16* qptr = qb + ((size_t)bh * TT + qrow0) * DH;
  bf16x8 aq[4];  // B-frags: q = col, d = dstep*16 + h*8 + j
#pragma unroll
  for (int dstep = 0; dstep < 4; ++dstep)
    aq[dstep] = *reinterpret_cast<const bf16x8*>(qptr + col * DH + dstep * 16 + h * 8);

  f32x16 acc[2];  // O^T: d = df*32 + (r&3)+8*(r>>2)+4h, q = col
#pragma unroll
  for (int df = 0; df < 2; ++df)
#pragma unroll
    for (int r = 0; r < 16; ++r) acc[df][r] = 0.f;
  float m_run = -1e30f, l_run = 0.f;

  const u16* kbase = kb + (size_t)bh * TT * DH;
  const u16* vbase = vtb + (size_t)bh * DH * TT;

  __syncthreads();  // publish mask/mflag (the only pre-loop barrier)
  const u32 fm = mflag;

  bf16x8 k0[8], k1[8], vv[8];
  LOADK_SET(0, k0);

#define COMPUTE_TILE(T, KA)                                                           \
  do {                                                                                \
    const int t_ = (T);                                                               \
    f32x16 sc[2];                                                                     \
    _Pragma("unroll") for (int kf = 0; kf < 2; ++kf)                                  \
      _Pragma("unroll") for (int r = 0; r < 16; ++r) sc[kf][r] = 0.f;                 \
    _Pragma("unroll") for (int dstep = 0; dstep < 4; ++dstep)                         \
      _Pragma("unroll") for (int kf = 0; kf < 2; ++kf)                                \
        sc[kf] = __builtin_amdgcn_mfma_f32_32x32x16_bf16(KA[kf * 4 + dstep],          \
                                                         aq[dstep], sc[kf], 0, 0, 0);\
    if (fm & (1u << t_)) {                                                            \
      _Pragma("unroll") for (int kf = 0; kf < 2; ++kf)                                \
        _Pragma("unroll") for (int r = 0; r < 16; ++r) {                              \
          int key = kf * 32 + (r & 3) + 8 * (r >> 2) + 4 * h;                         \
          sc[kf][r] += maskb[t_ * KVB + key] ? -1e30f : 0.f;                          \
        }                                                                             \
    }                                                                                 \
    {                                                                                 \
      float t0 = max3f(sc[0][0], sc[0][1], sc[0][2]);                                 \
      float t1 = max3f(sc[0][3], sc[0][4], sc[0][5]);                                 \
      float t2 = max3f(sc[0][6], sc[0][7], sc[0][8]);                                 \
      float t3 = max3f(sc[0][9], sc[0][10], sc[0][11]);                               \
      float t4 = max3f(sc[0][12], sc[0][13], sc[0][14]);                              \
      float t5 = max3f(sc[0][15], sc[1][0], sc[1][1]);                                \
      float t6 = max3f(sc[1][2], sc[1][3], sc[1][4]);                                 \
      float t7 = max3f(sc[1][5], sc[1][6], sc[1][7]);                                 \
      float t8 = max3f(sc[1][8], sc[1][9], sc[1][10]);                                \
      float t9 = max3f(sc[1][11], sc[1][12], sc[1][13]);                              \
      float ta = fmaxf(sc[1][14], sc[1][15]);                                         \
      float mx = fmaxf(max3f(max3f(t0, t1, t2), max3f(t3, t4, t5),                    \
                             max3f(t6, t7, t8)), max3f(t9, ta, -1e30f));              \
      mx = fmaxf(mx, __shfl_xor(mx, 32, 64));                                         \
      if (__any(mx > m_run + 8.0f)) {                                                 \
        float mn = fmaxf(m_run, mx);                                                  \
        float corr = fexp2(m_run - mn);                                               \
        m_run = mn;                                                                   \
        l_run *= corr;                                                                \
        _Pragma("unroll") for (int df = 0; df < 2; ++df)                              \
          _Pragma("unroll") for (int r = 0; r < 16; ++r) acc[df][r] *= corr;          \
      }                                                                               \
      const float mc = m_run;                                                         \
      float rs = 0.f;                                                                 \
      _Pragma("unroll") for (int kf = 0; kf < 2; ++kf)                                \
        _Pragma("unroll") for (int r = 0; r < 16; ++r) {                              \
          float p = fexp2(sc[kf][r] - mc);                                            \
          sc[kf][r] = p;                                                              \
          rs += p;                                                                    \
        }                                                                             \
      rs += __shfl_xor(rs, 32, 64);                                                   \
      l_run += rs;                                                                    \
    }                                                                                 \
    u32 P2[2][8];                                                                     \
    _Pragma("unroll") for (int kf = 0; kf < 2; ++kf)                                  \
      _Pragma("unroll") for (int i = 0; i < 8; ++i)                                   \
        P2[kf][i] = pk2bf(sc[kf][2 * i], sc[kf][2 * i + 1]);                          \
    __builtin_amdgcn_s_setprio(1);                                                    \
    _Pragma("unroll") for (int ksl = 0; ksl < 4; ++ksl) {                             \
      const int kf = ksl >> 1;                                                        \
      const int i0 = (ksl & 1) * 4;                                                   \
      u32 w0 = P2[kf][i0], w2 = P2[kf][i0 + 2];                                       \
      u32 w1 = P2[kf][i0 + 1], w3 = P2[kf][i0 + 3];                                   \
      asm("v_permlane32_swap_b32 %0, %1" : "+v"(w0), "+v"(w2));                       \
      asm("v_permlane32_swap_b32 %0, %1" : "+v"(w1), "+v"(w3));                       \
      u32 bpw[4] = {w0, w1, w2, w3};                                                  \
      bf16x8 bp = __builtin_bit_cast(bf16x8, *reinterpret_cast<uint4*>(bpw));         \
      _Pragma("unroll") for (int df = 0; df < 2; ++df)                                \
        acc[df] = __builtin_amdgcn_mfma_f32_32x32x16_bf16(vv[df * 4 + ksl], bp,       \
                                                          acc[df], 0, 0, 0);          \
    }                                                                                 \
    __builtin_amdgcn_s_setprio(0);                                                    \
  } while (0)

  for (int t = 0; t < TT / KVB; t += 2) {
    LOADK_SET(t + 1, k1);      // K(t+1) in flight across all of tile t
    LOADV_SET(t, vv);          // V(t) in flight until PV(t) (~600 cyc)
    COMPUTE_TILE(t, k0);
    LOADK_SET((t + 2) & (TT / KVB - 1), k0);
    LOADV_SET(t + 1, vv);
    COMPUTE_TILE(t + 1, k1);
  }
#undef COMPUTE_TILE

  // ---- epilogue: O^T regs -> LDS [128 q][64 d] (swizzled) -> coalesced global ----
  {
    float inv = 1.f / l_run;
    const int q = w * 32 + col;
    const int swzq = (q ^ (q >> 3)) & 7;
#pragma unroll
    for (int df = 0; df < 2; ++df) {
#pragma unroll
      for (int a = 0; a < 4; ++a) {
        uint2 pk;
        pk.x = pk2bf(acc[df][4 * a] * inv, acc[df][4 * a + 1] * inv);
        pk.y = pk2bf(acc[df][4 * a + 2] * inv, acc[df][4 * a + 3] * inv);
        int d2 = df * 64 + a * 16 + h * 8;  // byte offset of d within 128B row
        int byte = q * 128 + (d2 ^ (swzq << 4));
        *reinterpret_cast<uint2*>(reinterpret_cast<char*>(Ol) + byte) = pk;
      }
    }
  }
  __syncthreads();
  {
    const int hh = bh & 15;
#pragma unroll
    for (int p = 0; p < 4; ++p) {
      int idx = p * 256 + tid;
      int q = idx >> 3, ch = idx & 7;
      int swzq = (q ^ (q >> 3)) & 7;
      uint4 v = *reinterpret_cast<const uint4*>(
          reinterpret_cast<const char*>(Ol) + q * 128 + ((ch * 16) ^ (swzq << 4)));
      size_t row = (size_t)(b * TT + qt * 128 + q);
      *reinterpret_cast<uint4*>(ob + row * DMODEL + hh * DH + ch * 8) = v;
    }
  }
}

extern "C" void kernel_launch(void* const* d_in, const int* in_sizes, int n_in,
                              void* d_out, int out_size, void* d_ws, size_t ws_size,
                              hipStream_t stream) {
  const float* x = (const float*)d_in[0];
  const unsigned char* mask = (const unsigned char*)d_in[1];
  const float* wqkv = (const float*)d_in[2];
  const float* wproj = (const float*)d_in[3];
  float* out = (float*)d_out;

  u16* xb     = (u16*)d_ws;
  u16* wqkvb  = xb    + (size_t)MM * DMODEL;
  u16* wprojb = wqkvb + (size_t)NQKV * DMODEL;
  u16* qb     = wprojb + (size_t)DMODEL * DMODEL;
  u16* kb     = qb + (size_t)MM * DMODEL;
  u16* vtb    = kb + (size_t)MM * DMODEL;
  u16* ob     = vtb + (size_t)MM * DMODEL;

  cvt_all<<<(N4X + N4W + N4P) / 256, 256, 0, stream>>>(x, wqkv, wproj, xb);
  qkv_gemm<<<dim3(NQKV / 128, MM / 128), 256, 0, stream>>>(xb, wqkvb, qb, kb, vtb);
  attn_kernel<<<dim3(BB * NH, TT / 128), 256, 0, stream>>>(qb, kb, vtb, mask, ob);
  proj_gemm<<<dim3(DMODEL / 128, MM / 128), 256, 0, stream>>>(ob, wprojb, out);
}

// Round 10
// 133.801 us; speedup vs baseline: 1.4728x; 1.4728x over previous
//
#include <hip/hip_runtime.h>
#include <hip/hip_bf16.h>

typedef unsigned short u16;
typedef unsigned int u32;
typedef __bf16 bf16x8 __attribute__((ext_vector_type(8)));
typedef float f32x4 __attribute__((ext_vector_type(4)));
typedef float f32x16 __attribute__((ext_vector_type(16)));

#define DMODEL 1024
#define NH 16
#define DH 64
#define BB 2
#define TT 2048
#define MM 4096   // BB*TT
#define NQKV 3072
#define KVB 128   // attention key-tile (128: halves barrier-convoy iterations)

// Q pre-scale: Dh^-0.5 * log2(e) -> scores land in log2 domain (P = v_exp_f32 direct)
#define QSCALE 0.18033688011112042f

static __device__ __forceinline__ u16 f2bf(float f) {
  u32 u = __float_as_uint(f);
  u = (u + 0x7FFFu + ((u >> 16) & 1u)) >> 16;  // RNE
  return (u16)u;
}

static __device__ __forceinline__ u32 pk2bf(float a, float b) {
  u16 ua = __builtin_bit_cast(u16, (__bf16)a);
  u16 ub = __builtin_bit_cast(u16, (__bf16)b);
  return (u32)ua | ((u32)ub << 16);
}

static __device__ __forceinline__ float fexp2(float x) {
#if __has_builtin(__builtin_amdgcn_exp2f)
  return __builtin_amdgcn_exp2f(x);
#else
  float r; asm("v_exp_f32 %0, %1" : "=v"(r) : "v"(x)); return r;
#endif
}

static __device__ __forceinline__ float max3f(float a, float b, float c) {
  return fmaxf(fmaxf(a, b), c);  // fuses to v_max3_f32
}

static __device__ __forceinline__ float maxv16(const f32x16& v) {
  float t0 = max3f(v[0], v[1], v[2]);
  float t1 = max3f(v[3], v[4], v[5]);
  float t2 = max3f(v[6], v[7], v[8]);
  float t3 = max3f(v[9], v[10], v[11]);
  float t4 = max3f(v[12], v[13], v[14]);
  return fmaxf(max3f(t0, t1, t2), max3f(t3, t4, v[15]));
}

static __device__ __forceinline__ void gload16(const u16* g, u16* l) {
  __builtin_amdgcn_global_load_lds(
      (const __attribute__((address_space(1))) void*)g,
      (__attribute__((address_space(3))) void*)l, 16, 0, 0);
}

// Fused f32->bf16 convert: x | wqkv | wproj (dst regions contiguous in ws).
#define N4X  (MM * DMODEL / 4)
#define N4W  (NQKV * DMODEL / 4)
#define N4P  (DMODEL * DMODEL / 4)
__global__ __launch_bounds__(256) void cvt_all(const float* __restrict__ x,
                                               const float* __restrict__ wqkv,
                                               const float* __restrict__ wproj,
                                               u16* __restrict__ dst) {
  int i = blockIdx.x * 256 + threadIdx.x;
  const float* src;
  int j = i;
  if (i < N4X) {
    src = x;
  } else if (i < N4X + N4W) {
    src = wqkv; j = i - N4X;
  } else {
    src = wproj; j = i - (N4X + N4W);
  }
  float4 v = reinterpret_cast<const float4*>(src)[j];
  ushort4 o;
  o.x = f2bf(v.x); o.y = f2bf(v.y); o.z = f2bf(v.z); o.w = f2bf(v.w);
  reinterpret_cast<ushort4*>(dst)[i] = o;
}

// ---------- GEMM: 128x128 tile, K=1024, 2-phase pipelined ----------
static __device__ __forceinline__ void gemm_stage(
    const u16* __restrict__ A, const u16* __restrict__ B, u16* As, u16* Bs,
    int r0, int o0, int r1, int o1, int c0, int c1, int kcol) {
  gload16(A + (size_t)r0 * DMODEL + kcol + o0, As + c0 * 8);
  gload16(A + (size_t)r1 * DMODEL + kcol + o1, As + c1 * 8);
  gload16(B + (size_t)r0 * DMODEL + kcol + o0, Bs + c0 * 8);
  gload16(B + (size_t)r1 * DMODEL + kcol + o1, Bs + c1 * 8);
}

static __device__ __forceinline__ void gemm128_mainloop(
    const u16* __restrict__ Abase, const u16* __restrict__ Bbase,
    u16* As, u16* Bs, f32x4 (&acc)[4][4]) {
  const int tid = threadIdx.x;
  const int lane = tid & 63;
  const int w = tid >> 6;
  const int rowg = lane >> 4, col = lane & 15;
  const int wm = w >> 1, wn = w & 1;
  const int c0 = tid, c1 = tid + 256;
  const int r0 = c0 >> 2, o0 = (c0 & 3) * 8;
  const int r1 = c1 >> 2, o1 = (c1 & 3) * 8;

  gemm_stage(Abase, Bbase, As, Bs, r0, o0, r1, o1, c0, c1, 0);
  asm volatile("s_waitcnt vmcnt(0)" ::: "memory");
  __builtin_amdgcn_s_barrier();

  int sel = 0;
  for (int kt = 0; kt < DMODEL / 32; ++kt) {
    const int kn = ((kt + 1) & (DMODEL / 32 - 1)) * 32;
    const int ns = sel ^ 1;
    gemm_stage(Abase, Bbase, As + ns * 4096, Bs + ns * 4096, r0, o0, r1, o1, c0, c1, kn);
    const u16* as = As + sel * 4096;
    const u16* bs = Bs + sel * 4096;
    bf16x8 af[4], bfr[4];
#pragma unroll
    for (int i = 0; i < 4; ++i)
      af[i] = *reinterpret_cast<const bf16x8*>(as + (wm * 64 + i * 16 + col) * 32 + rowg * 8);
#pragma unroll
    for (int j = 0; j < 4; ++j)
      bfr[j] = *reinterpret_cast<const bf16x8*>(bs + (wn * 64 + j * 16 + col) * 32 + rowg * 8);
#pragma unroll
    for (int i = 0; i < 4; ++i)
#pragma unroll
      for (int j = 0; j < 4; ++j)
        acc[i][j] = __builtin_amdgcn_mfma_f32_16x16x32_bf16(af[i], bfr[j], acc[i][j], 0, 0, 0);
    asm volatile("s_waitcnt vmcnt(0)" ::: "memory");
    __builtin_amdgcn_s_barrier();
    sel = ns;
  }
}

// QKV projection: C[m,n] = x[m,:] . Wqkv[n,:]; scatter to q/k/vt, q pre-scaled.
__global__ __launch_bounds__(256, 3) void qkv_gemm(
    const u16* __restrict__ xb, const u16* __restrict__ wb,
    u16* __restrict__ qb, u16* __restrict__ kb, u16* __restrict__ vtb) {
  __shared__ u16 As[2 * 128 * 32];
  __shared__ u16 Bs[2 * 128 * 32];
  f32x4 acc[4][4];
#pragma unroll
  for (int i = 0; i < 4; ++i)
#pragma unroll
    for (int j = 0; j < 4; ++j) acc[i][j] = (f32x4){0.f, 0.f, 0.f, 0.f};
  gemm128_mainloop(xb + (size_t)blockIdx.y * 128 * DMODEL,
                   wb + (size_t)blockIdx.x * 128 * DMODEL, As, Bs, acc);
  const int lane = threadIdx.x & 63, w = threadIdx.x >> 6;
  const int rowg = lane >> 4, col = lane & 15, wm = w >> 1, wn = w & 1;
#pragma unroll
  for (int i = 0; i < 4; ++i) {
#pragma unroll
    for (int j = 0; j < 4; ++j) {
#pragma unroll
      for (int r = 0; r < 4; ++r) {
        int m = blockIdx.y * 128 + wm * 64 + i * 16 + rowg * 4 + r;
        int n = blockIdx.x * 128 + wn * 64 + j * 16 + col;
        int b = m >> 11, t = m & (TT - 1);
        int s = n >> 10, h = (n >> 6) & 15, d = n & 63;
        int bh = b * NH + h;
        float v = acc[i][j][r];
        if (s == 0)      qb[((size_t)bh * TT + t) * DH + d] = f2bf(v * QSCALE);
        else if (s == 1) kb[((size_t)bh * TT + t) * DH + d] = f2bf(v);
        else             vtb[((size_t)bh * DH + d) * TT + t] = f2bf(v);
      }
    }
  }
}

// Output projection: out[m,n] = ob[m,:] . Wproj[n,:], f32 out.
__global__ __launch_bounds__(256, 3) void proj_gemm(
    const u16* __restrict__ ab, const u16* __restrict__ wb, float* __restrict__ out) {
  __shared__ u16 As[2 * 128 * 32];
  __shared__ u16 Bs[2 * 128 * 32];
  f32x4 acc[4][4];
#pragma unroll
  for (int i = 0; i < 4; ++i)
#pragma unroll
    for (int j = 0; j < 4; ++j) acc[i][j] = (f32x4){0.f, 0.f, 0.f, 0.f};
  gemm128_mainloop(ab + (size_t)blockIdx.y * 128 * DMODEL,
                   wb + (size_t)blockIdx.x * 128 * DMODEL, As, Bs, acc);
  const int lane = threadIdx.x & 63, w = threadIdx.x >> 6;
  const int rowg = lane >> 4, col = lane & 15, wm = w >> 1, wn = w & 1;
#pragma unroll
  for (int i = 0; i < 4; ++i) {
#pragma unroll
    for (int j = 0; j < 4; ++j) {
#pragma unroll
      for (int r = 0; r < 4; ++r) {
        int m = blockIdx.y * 128 + wm * 64 + i * 16 + rowg * 4 + r;
        int n = blockIdx.x * 128 + wn * 64 + j * 16 + col;
        out[(size_t)m * DMODEL + n] = acc[i][j][r];
      }
    }
  }
}

// ---------- Flash attention: 4 waves x 32 q, 32x32x16 MFMA, in-register P, KVB=128 ----------
// r8 structure (LDS-staged K/V, 2-phase, in-reg P via cvt_pk+permlane) with the key-tile
// doubled: 16 iterations instead of 32 -> barrier/drain overhead halved per key.
static __device__ __forceinline__ void attn_stage(
    const u16* __restrict__ kbase, const u16* __restrict__ vbase,
    int kt, u16* KsSel, u16* VsSel, int tid) {
  // K tile [128 key][64 d] = 16KB: rows 128B, swizzle (row&7)<<4
#pragma unroll
  for (int p = 0; p < 4; ++p) {
    int c = p * 256 + tid;
    int row = c >> 3;
    int bI = (c & 7) * 16;
    gload16(kbase + kt * (KVB * DH) + row * DH + ((bI ^ ((row & 7) << 4)) >> 1), KsSel + c * 8);
  }
  // V tile [64 d][128 key] = 16KB: rows 256B, swizzle (d&7)<<4 (r1-verified 256B-row form)
#pragma unroll
  for (int p = 0; p < 4; ++p) {
    int c = p * 256 + tid;
    int d = c >> 4;
    int bI = (c & 15) * 16;
    gload16(vbase + (size_t)d * TT + kt * KVB + ((bI ^ ((d & 7) << 4)) >> 1), VsSel + c * 8);
  }
}

__global__ __launch_bounds__(256, 2) void attn_kernel(
    const u16* __restrict__ qb, const u16* __restrict__ kb,
    const u16* __restrict__ vtb, const unsigned char* __restrict__ mask,
    u16* __restrict__ ob) {
  __shared__ u16 SM[2][2][KVB * DH];   // [buf][K|V][16KB]; 64KB total. Epilogue reuses 16KB.
  __shared__ unsigned char maskb[TT];
  __shared__ u32 mflag;

  const int tid = threadIdx.x;
  const int lane = tid & 63, w = tid >> 6;
  const int col = lane & 31, h = lane >> 5;
  const int qt = blockIdx.x, bh = blockIdx.y;
  const int b = bh >> 4;

  if (tid == 0) mflag = 0;
  __syncthreads();

  {  // preload mask bytes; per-tile flag bits (8B/thread; tile = 128B -> bit tid>>4)
    const u32* mg = reinterpret_cast<const u32*>(mask + (size_t)b * TT);
    u32 m0 = mg[tid * 2], m1 = mg[tid * 2 + 1];
    *reinterpret_cast<u32*>(maskb + tid * 8) = m0;
    *reinterpret_cast<u32*>(maskb + tid * 8 + 4) = m1;
    if (m0 | m1) atomicOr(&mflag, 1u << (tid >> 4));
  }

  const int qrow0 = qt * 128 + w * 32;
  const u16* qptr = qb + ((size_t)bh * TT + qrow0) * DH;
  bf16x8 aq[4];  // B-frags: q = col, d = dstep*16 + h*8 + j
#pragma unroll
  for (int dstep = 0; dstep < 4; ++dstep)
    aq[dstep] = *reinterpret_cast<const bf16x8*>(qptr + col * DH + dstep * 16 + h * 8);

  f32x16 acc[2];  // O^T: d = df*32 + (r&3)+8*(r>>2)+4h, q = col
#pragma unroll
  for (int df = 0; df < 2; ++df)
#pragma unroll
    for (int r = 0; r < 16; ++r) acc[df][r] = 0.f;
  float m_run = -1e30f, l_run = 0.f;

  const u16* kbase = kb + (size_t)bh * TT * DH;
  const u16* vbase = vtb + (size_t)bh * DH * TT;

  attn_stage(kbase, vbase, 0, SM[0][0], SM[0][1], tid);
  __syncthreads();  // drains prologue stage + publishes mask/mflag
  const u32 fm = mflag;

  int cur = 0;
  for (int t = 0; t < TT / KVB; ++t) {
    const int tn = (t + 1) & (TT / KVB - 1);
    attn_stage(kbase, vbase, tn, SM[cur ^ 1][0], SM[cur ^ 1][1], tid);

    const u16* ks = SM[cur][0];
    const u16* vs = SM[cur][1];

    // ---- S^T = K . Q^T : sc[kf] f32x16, key = kf*32 + (r&3)+8*(r>>2)+4h, q = col ----
    f32x16 sc[4];
#pragma unroll
    for (int kf = 0; kf < 4; ++kf)
#pragma unroll
      for (int r = 0; r < 16; ++r) sc[kf][r] = 0.f;
#pragma unroll
    for (int dstep = 0; dstep < 4; ++dstep) {
      bf16x8 ak[4];
#pragma unroll
      for (int kf = 0; kf < 4; ++kf) {
        int row = kf * 32 + col;
        ak[kf] = *reinterpret_cast<const bf16x8*>(
            ks + row * DH + (((dstep * 32 + h * 16) ^ ((row & 7) << 4)) >> 1));
      }
#pragma unroll
      for (int kf = 0; kf < 4; ++kf)
        sc[kf] = __builtin_amdgcn_mfma_f32_32x32x16_bf16(ak[kf], aq[dstep], sc[kf], 0, 0, 0);
    }

    if (fm & (1u << t)) {  // rare path: additive mask per key
#pragma unroll
      for (int kf = 0; kf < 4; ++kf)
#pragma unroll
        for (int r = 0; r < 16; ++r) {
          int key = kf * 32 + (r & 3) + 8 * (r >> 2) + 4 * h;
          sc[kf][r] += maskb[t * KVB + key] ? -1e30f : 0.f;
        }
    }

    // ---- online softmax (log2 domain): lane-local max over 64 + 1 shfl; defer-rescale ----
    u32 P2[4][8];
    {
      float mk0 = maxv16(sc[0]), mk1 = maxv16(sc[1]);
      float mk2 = maxv16(sc[2]), mk3 = maxv16(sc[3]);
      float mx = fmaxf(fmaxf(mk0, mk1), fmaxf(mk2, mk3));
      mx = fmaxf(mx, __shfl_xor(mx, 32, 64));  // lane pair (h0,h1) holds disjoint keys
      if (__any(mx > m_run + 8.0f)) {
        float mn = fmaxf(m_run, mx);
        float corr = fexp2(m_run - mn);
        m_run = mn;
        l_run *= corr;
#pragma unroll
        for (int df = 0; df < 2; ++df)
#pragma unroll
          for (int r = 0; r < 16; ++r) acc[df][r] *= corr;
      }
      const float mc = m_run;
      float rs = 0.f;
#pragma unroll
      for (int kf = 0; kf < 4; ++kf) {
#pragma unroll
        for (int i = 0; i < 8; ++i) {
          float p0 = fexp2(sc[kf][2 * i] - mc);
          float p1 = fexp2(sc[kf][2 * i + 1] - mc);
          rs += p0 + p1;
          P2[kf][i] = pk2bf(p0, p1);
        }
      }
      rs += __shfl_xor(rs, 32, 64);
      l_run += rs;
    }

    // ---- O^T += V^T . P^T : per 16-key slice, B-frag words via permlane32_swap ----
    __builtin_amdgcn_s_setprio(1);
#pragma unroll
    for (int ksl = 0; ksl < 8; ++ksl) {
      const int kf = ksl >> 1;
      const int i0 = (ksl & 1) * 4;
      u32 w0 = P2[kf][i0],     w2 = P2[kf][i0 + 2];
      u32 w1 = P2[kf][i0 + 1], w3 = P2[kf][i0 + 3];
      asm("v_permlane32_swap_b32 %0, %1" : "+v"(w0), "+v"(w2));
      asm("v_permlane32_swap_b32 %0, %1" : "+v"(w1), "+v"(w3));
      u32 bpw[4] = {w0, w1, w2, w3};
      bf16x8 bp = __builtin_bit_cast(bf16x8, *reinterpret_cast<uint4*>(bpw));
#pragma unroll
      for (int df = 0; df < 2; ++df) {
        int row = df * 32 + col;  // d-row of V^T (256B rows)
        bf16x8 av = *reinterpret_cast<const bf16x8*>(
            vs + row * KVB + (((ksl * 32 + h * 16) ^ ((row & 7) << 4)) >> 1));
        acc[df] = __builtin_amdgcn_mfma_f32_32x32x16_bf16(av, bp, acc[df], 0, 0, 0);
      }
    }
    __builtin_amdgcn_s_setprio(0);

    asm volatile("s_waitcnt vmcnt(0)" ::: "memory");
    __builtin_amdgcn_s_barrier();
    cur ^= 1;
  }

  // ---- epilogue: O^T regs -> LDS [128 q][64 d] (swizzled) -> coalesced global ----
  u16* Ol = &SM[0][0][0];  // 16KB of the staging region (post-barrier, safe)
  {
    float inv = 1.f / l_run;
    const int q = w * 32 + col;
    const int swzq = (q ^ (q >> 3)) & 7;
#pragma unroll
    for (int df = 0; df < 2; ++df) {
#pragma unroll
      for (int a = 0; a < 4; ++a) {
        uint2 pk;
        pk.x = pk2bf(acc[df][4 * a] * inv, acc[df][4 * a + 1] * inv);
        pk.y = pk2bf(acc[df][4 * a + 2] * inv, acc[df][4 * a + 3] * inv);
        int d2 = df * 64 + a * 16 + h * 8;  // byte offset of d within 128B row
        int byte = q * 128 + (d2 ^ (swzq << 4));
        *reinterpret_cast<uint2*>(reinterpret_cast<char*>(Ol) + byte) = pk;
      }
    }
  }
  __syncthreads();
  {
    const int hh = bh & 15;
#pragma unroll
    for (int p = 0; p < 4; ++p) {
      int idx = p * 256 + tid;
      int q = idx >> 3, ch = idx & 7;
      int swzq = (q ^ (q >> 3)) & 7;
      uint4 v = *reinterpret_cast<const uint4*>(
          reinterpret_cast<const char*>(Ol) + q * 128 + ((ch * 16) ^ (swzq << 4)));
      size_t row = (size_t)(b * TT + qt * 128 + q);
      *reinterpret_cast<uint4*>(ob + row * DMODEL + hh * DH + ch * 8) = v;
    }
  }
}

extern "C" void kernel_launch(void* const* d_in, const int* in_sizes, int n_in,
                              void* d_out, int out_size, void* d_ws, size_t ws_size,
                              hipStream_t stream) {
  const float* x = (const float*)d_in[0];
  const unsigned char* mask = (const unsigned char*)d_in[1];
  const float* wqkv = (const float*)d_in[2];
  const float* wproj = (const float*)d_in[3];
  float* out = (float*)d_out;

  u16* xb     = (u16*)d_ws;
  u16* wqkvb  = xb    + (size_t)MM * DMODEL;
  u16* wprojb = wqkvb + (size_t)NQKV * DMODEL;
  u16* qb     = wprojb + (size_t)DMODEL * DMODEL;
  u16* kb     = qb + (size_t)MM * DMODEL;
  u16* vtb    = kb + (size_t)MM * DMODEL;
  u16* ob     = vtb + (size_t)MM * DMODEL;

  cvt_all<<<(N4X + N4W + N4P) / 256, 256, 0, stream>>>(x, wqkv, wproj, xb);
  qkv_gemm<<<dim3(NQKV / 128, MM / 128), 256, 0, stream>>>(xb, wqkvb, qb, kb, vtb);
  attn_kernel<<<dim3(TT / 128, BB * NH), 256, 0, stream>>>(qb, kb, vtb, mask, ob);
  proj_gemm<<<dim3(DMODEL / 128, MM / 128), 256, 0, stream>>>(ob, wprojb, out);
}